// Round 8
// baseline (881.992 us; speedup 1.0000x reference)
//
#include <hip/hip_runtime.h>

#define N_NODES 50000
#define EPS 1e-6f
#define NB 782          // buckets of 64 nodes: ceil(50000/64)
#define NBPAD 1024
#define NPAD 50048      // N rounded up to 64 (mean1/g padded rows)
#define FILL_CHUNK 12288

// ---------------- Workspace layout (ints then floats) ----------------
// bcnt   : 1024 ints (zeroed each call; bucket histogram)
// bstart : 1028 ints (bucket CSR offsets, bstart[NB] = E)
// bcur   : 1024 ints (fill cursors)
// packed : E ints    ((src<<16)|dst, grouped by bucket)
// mean1  : NPAD*64 floats
// g      : NPAD*64 floats
//
// NUMERICS CONTRACT: absmax pinned at 0.03125 empirically.
//  - neighbor-sum ORDER is free (round-1 global float atomics measured
//    0.03125), but per-element epilogue EXPRESSIONS are not:
//    mean = acc*dinv (dinv=1/(deg+EPS)); val = acc*dinv + b2;
//    softmax: lane-xor butterfly 8,4,2,1 then (x+z)+(y+w); (val-mx)-logf(sm).
//  - GEMMs: acc init (bias/0), fmaf over ascending k, one chain per output.
// SCHEDULE CONTRACT (round-6): constant-trip k-loops containing global loads
// MUST carry #pragma unroll 1 (else full unroll -> VGPR 256 -> scratch spill).

#define COMP(v, j) ((j) == 0 ? (v).x : (j) == 1 ? (v).y : (j) == 2 ? (v).z : (v).w)

// ---- Bucket histogram: 782 bins, LDS-staged ----
__global__ __launch_bounds__(256) void bhist_kernel(
    const int* __restrict__ dst, int* __restrict__ bcnt, int E) {
  __shared__ int lb[NBPAD];
  int t = threadIdx.x;
  for (int i = t; i < NBPAD; i += 256) lb[i] = 0;
  __syncthreads();
  int base = blockIdx.x * 4096;
  for (int i = t; i < 4096; i += 256) {
    int e = base + i;
    if (e < E) atomicAdd(&lb[dst[e] >> 6], 1);
  }
  __syncthreads();
  for (int i = t; i < NB; i += 256) {
    int c = lb[i];
    if (c) atomicAdd(&bcnt[i], c);
  }
}

// ---- Bucket scan: one block, 1024 bins (4/thread) ----
__global__ __launch_bounds__(256) void bscan_kernel(
    const int* __restrict__ bcnt, int* __restrict__ bstart,
    int* __restrict__ bcur) {
  __shared__ int wsum[4];
  int t = threadIdx.x;
  int i0 = t * 4;
  int v0 = (i0 + 0 < NB) ? bcnt[i0 + 0] : 0;
  int v1 = (i0 + 1 < NB) ? bcnt[i0 + 1] : 0;
  int v2 = (i0 + 2 < NB) ? bcnt[i0 + 2] : 0;
  int v3 = (i0 + 3 < NB) ? bcnt[i0 + 3] : 0;
  int s = ((v0 + v1) + (v2 + v3));
  int lane = t & 63, wv = t >> 6;
  int x = s;
#pragma unroll
  for (int d = 1; d < 64; d <<= 1) {
    int y = __shfl_up(x, d, 64);
    if (lane >= d) x += y;
  }
  if (lane == 63) wsum[wv] = x;
  __syncthreads();
  int add = 0;
  for (int w = 0; w < wv; w++) add += wsum[w];
  int excl = add + x - s;
  int p0 = excl, p1 = p0 + v0, p2 = p1 + v1, p3 = p2 + v2;
  if (i0 + 0 < NB) { bstart[i0 + 0] = p0; bcur[i0 + 0] = p0; }
  if (i0 + 1 < NB) { bstart[i0 + 1] = p1; bcur[i0 + 1] = p1; }
  if (i0 + 2 < NB) { bstart[i0 + 2] = p2; bcur[i0 + 2] = p2; }
  if (i0 + 3 < NB) { bstart[i0 + 3] = p3; bcur[i0 + 3] = p3; }
  if (t == 255) bstart[NB] = excl + s;  // = E
}

// ---- Bucket fill: per-block LDS hist -> one global reservation per bucket
// -> scatter packed edges. Runs are block-contiguous => L2 merges stores.
__global__ __launch_bounds__(256) void bfill_kernel(
    const int* __restrict__ src, const int* __restrict__ dst,
    int* __restrict__ bcur, int* __restrict__ packed, int E) {
  __shared__ int lb[NBPAD];
  __shared__ int lcur[NBPAD];
  int t = threadIdx.x;
  for (int i = t; i < NBPAD; i += 256) lb[i] = 0;
  __syncthreads();
  int base = blockIdx.x * FILL_CHUNK;
  int end = base + FILL_CHUNK; if (end > E) end = E;
  for (int e = base + t; e < end; e += 256) atomicAdd(&lb[dst[e] >> 6], 1);
  __syncthreads();
  for (int i = t; i < NB; i += 256) {
    int c = lb[i];
    lcur[i] = c ? atomicAdd(&bcur[i], c) : 0;
  }
  __syncthreads();
  for (int e = base + t; e < end; e += 256) {
    int d = dst[e];
    int pos = atomicAdd(&lcur[d >> 6], 1);
    packed[pos] = (int)(((unsigned)src[e] << 16) | (unsigned)d);
  }
}

// ---- Bucketed gather 1: one block per bucket; LDS float-atomic accumulate.
// lane = feature (64); 4-edge unroll for load ILP.
__global__ __launch_bounds__(256) void bgather1_kernel(
    const float* __restrict__ x, const int* __restrict__ bstart,
    const int* __restrict__ packed, float* __restrict__ mean1) {
  __shared__ float acc[64][68];
  __shared__ float deg[64];
  int t = threadIdx.x;
  for (int i = t; i < 64 * 68; i += 256) (&acc[0][0])[i] = 0.0f;
  if (t < 64) deg[t] = 0.0f;
  __syncthreads();
  int b = blockIdx.x;
  int nodeBase = b << 6;
  int eb = bstart[b], ee = bstart[b + 1];
  int lane = t & 63, wav = t >> 6;
  for (int base = eb + wav * 64; base < ee; base += 256) {
    int rem = ee - base; if (rem > 64) rem = 64;
    int pk = (lane < rem) ? packed[base + lane] : 0;
    int j = 0;
    for (; j + 4 <= rem; j += 4) {
      int p0 = __shfl(pk, j, 64);
      int p1 = __shfl(pk, j + 1, 64);
      int p2 = __shfl(pk, j + 2, 64);
      int p3 = __shfl(pk, j + 3, 64);
      float v0 = x[(size_t)(((unsigned)p0) >> 16) * 64 + lane];
      float v1 = x[(size_t)(((unsigned)p1) >> 16) * 64 + lane];
      float v2 = x[(size_t)(((unsigned)p2) >> 16) * 64 + lane];
      float v3 = x[(size_t)(((unsigned)p3) >> 16) * 64 + lane];
      atomicAdd(&acc[(p0 & 0xffff) - nodeBase][lane], v0);
      atomicAdd(&acc[(p1 & 0xffff) - nodeBase][lane], v1);
      atomicAdd(&acc[(p2 & 0xffff) - nodeBase][lane], v2);
      atomicAdd(&acc[(p3 & 0xffff) - nodeBase][lane], v3);
    }
    for (; j < rem; j++) {
      int p = __shfl(pk, j, 64);
      float v = x[(size_t)(((unsigned)p) >> 16) * 64 + lane];
      atomicAdd(&acc[(p & 0xffff) - nodeBase][lane], v);
    }
    if (lane < rem) atomicAdd(&deg[(pk & 0xffff) - nodeBase], 1.0f);
  }
  __syncthreads();
  for (int i = t; i < 64 * 64; i += 256) {
    int n = i >> 6, f = i & 63;
    float dinv = 1.0f / (deg[n] + EPS);
    mean1[(size_t)(nodeBase + n) * 64 + f] = acc[n][f] * dinv;
  }
}

// ---- Fused MLP (unchanged from round 7) ----
__global__ __launch_bounds__(256, 3) void mlp_fused_kernel(
    const float* __restrict__ mean1, const float* __restrict__ W1,
    const float* __restrict__ b1, const float* __restrict__ W2,
    float* __restrict__ g) {
  __shared__ float sM[64][68];
  __shared__ float sH[64][132];
  int t = threadIdx.x;
  int row0 = blockIdx.x * 64;

  {
    const float4* M4 = (const float4*)(mean1 + (size_t)row0 * 64);
#pragma unroll
    for (int i = 0; i < 4; i++) {
      int idx = t + 256 * i;
      *(float4*)&sM[idx >> 4][(idx & 15) << 2] = M4[idx];
    }
  }
  __syncthreads();

  int tc = t & 15;
  int tr = t >> 4;

  {  // GEMM1 + relu -> sH
    int c = tc << 3;
    int r = tr << 2;
    float acc[4][8];
    float4 bA = *(const float4*)(b1 + c);
    float4 bB = *(const float4*)(b1 + c + 4);
#pragma unroll
    for (int i = 0; i < 4; i++) {
      acc[i][0] = bA.x; acc[i][1] = bA.y; acc[i][2] = bA.z; acc[i][3] = bA.w;
      acc[i][4] = bB.x; acc[i][5] = bB.y; acc[i][6] = bB.z; acc[i][7] = bB.w;
    }
#pragma unroll 1
    for (int k = 0; k < 64; k += 4) {
      float4 a[4];
#pragma unroll
      for (int i = 0; i < 4; i++) a[i] = *(const float4*)&sM[r + i][k];
      float4 wA[4], wB[4];
#pragma unroll
      for (int j = 0; j < 4; j++) {
        const float* wrow = W1 + (size_t)(k + j) * 128 + c;
        wA[j] = *(const float4*)wrow;
        wB[j] = *(const float4*)(wrow + 4);
      }
#pragma unroll
      for (int j = 0; j < 4; j++) {
#pragma unroll
        for (int i = 0; i < 4; i++) {
          float av = COMP(a[i], j);
          acc[i][0] = fmaf(av, wA[j].x, acc[i][0]);
          acc[i][1] = fmaf(av, wA[j].y, acc[i][1]);
          acc[i][2] = fmaf(av, wA[j].z, acc[i][2]);
          acc[i][3] = fmaf(av, wA[j].w, acc[i][3]);
          acc[i][4] = fmaf(av, wB[j].x, acc[i][4]);
          acc[i][5] = fmaf(av, wB[j].y, acc[i][5]);
          acc[i][6] = fmaf(av, wB[j].z, acc[i][6]);
          acc[i][7] = fmaf(av, wB[j].w, acc[i][7]);
        }
      }
    }
#pragma unroll
    for (int i = 0; i < 4; i++) {
      float4 h0, h1v;
      h0.x = fmaxf(acc[i][0], 0.f); h0.y = fmaxf(acc[i][1], 0.f);
      h0.z = fmaxf(acc[i][2], 0.f); h0.w = fmaxf(acc[i][3], 0.f);
      h1v.x = fmaxf(acc[i][4], 0.f); h1v.y = fmaxf(acc[i][5], 0.f);
      h1v.z = fmaxf(acc[i][6], 0.f); h1v.w = fmaxf(acc[i][7], 0.f);
      *(float4*)&sH[r + i][c] = h0;
      *(float4*)&sH[r + i][c + 4] = h1v;
    }
  }
  __syncthreads();

  {  // GEMM2 -> g
    int c = tc << 2;
    int r = tr << 2;
    float acc[4][4];
#pragma unroll
    for (int i = 0; i < 4; i++)
      acc[i][0] = acc[i][1] = acc[i][2] = acc[i][3] = 0.f;
#pragma unroll 1
    for (int k = 0; k < 128; k += 4) {
      float4 a[4];
#pragma unroll
      for (int i = 0; i < 4; i++) a[i] = *(const float4*)&sH[r + i][k];
      float4 w[4];
#pragma unroll
      for (int j = 0; j < 4; j++)
        w[j] = *(const float4*)(W2 + (size_t)(k + j) * 64 + c);
#pragma unroll
      for (int j = 0; j < 4; j++) {
#pragma unroll
        for (int i = 0; i < 4; i++) {
          float av = COMP(a[i], j);
          acc[i][0] = fmaf(av, w[j].x, acc[i][0]);
          acc[i][1] = fmaf(av, w[j].y, acc[i][1]);
          acc[i][2] = fmaf(av, w[j].z, acc[i][2]);
          acc[i][3] = fmaf(av, w[j].w, acc[i][3]);
        }
      }
    }
#pragma unroll
    for (int i = 0; i < 4; i++) {
      int row = row0 + r + i;
      if (row < N_NODES) {
        float4 o4;
        o4.x = acc[i][0]; o4.y = acc[i][1]; o4.z = acc[i][2]; o4.w = acc[i][3];
        *(float4*)(g + (size_t)row * 64 + c) = o4;
      }
    }
  }
}

// ---- Bucketed gather 2 + bias + log_softmax ----
__global__ __launch_bounds__(256) void bgather2_kernel(
    const float* __restrict__ g, const int* __restrict__ bstart,
    const int* __restrict__ packed, const float* __restrict__ b2,
    float* __restrict__ out) {
  __shared__ float acc[64][68];
  __shared__ float deg[64];
  int t = threadIdx.x;
  for (int i = t; i < 64 * 68; i += 256) (&acc[0][0])[i] = 0.0f;
  if (t < 64) deg[t] = 0.0f;
  __syncthreads();
  int b = blockIdx.x;
  int nodeBase = b << 6;
  int eb = bstart[b], ee = bstart[b + 1];
  int lane = t & 63, wav = t >> 6;
  for (int base = eb + wav * 64; base < ee; base += 256) {
    int rem = ee - base; if (rem > 64) rem = 64;
    int pk = (lane < rem) ? packed[base + lane] : 0;
    int j = 0;
    for (; j + 4 <= rem; j += 4) {
      int p0 = __shfl(pk, j, 64);
      int p1 = __shfl(pk, j + 1, 64);
      int p2 = __shfl(pk, j + 2, 64);
      int p3 = __shfl(pk, j + 3, 64);
      float v0 = g[(size_t)(((unsigned)p0) >> 16) * 64 + lane];
      float v1 = g[(size_t)(((unsigned)p1) >> 16) * 64 + lane];
      float v2 = g[(size_t)(((unsigned)p2) >> 16) * 64 + lane];
      float v3 = g[(size_t)(((unsigned)p3) >> 16) * 64 + lane];
      atomicAdd(&acc[(p0 & 0xffff) - nodeBase][lane], v0);
      atomicAdd(&acc[(p1 & 0xffff) - nodeBase][lane], v1);
      atomicAdd(&acc[(p2 & 0xffff) - nodeBase][lane], v2);
      atomicAdd(&acc[(p3 & 0xffff) - nodeBase][lane], v3);
    }
    for (; j < rem; j++) {
      int p = __shfl(pk, j, 64);
      float v = g[(size_t)(((unsigned)p) >> 16) * 64 + lane];
      atomicAdd(&acc[(p & 0xffff) - nodeBase][lane], v);
    }
    if (lane < rem) atomicAdd(&deg[(pk & 0xffff) - nodeBase], 1.0f);
  }
  __syncthreads();

  // log_softmax epilogue: round-5 tree, 4 nodes per wave per round.
  int sub = lane >> 4, l16 = lane & 15;
  float4 b2v = ((const float4*)b2)[l16];
  for (int r = 0; r < 4; r++) {
    int n = (wav << 4) + (r << 2) + sub;
    float dinv = 1.0f / (deg[n] + EPS);
    float4 a = *(const float4*)&acc[n][l16 << 2];
    float4 val;
    val.x = a.x * dinv + b2v.x;
    val.y = a.y * dinv + b2v.y;
    val.z = a.z * dinv + b2v.z;
    val.w = a.w * dinv + b2v.w;

    float4 m = val;
#pragma unroll
    for (int o = 8; o > 0; o >>= 1) {
      m.x = fmaxf(m.x, __shfl_xor(m.x, o, 64));
      m.y = fmaxf(m.y, __shfl_xor(m.y, o, 64));
      m.z = fmaxf(m.z, __shfl_xor(m.z, o, 64));
      m.w = fmaxf(m.w, __shfl_xor(m.w, o, 64));
    }
    float mx = fmaxf(fmaxf(m.x, m.z), fmaxf(m.y, m.w));

    float4 ex;
    ex.x = __expf(val.x - mx);
    ex.y = __expf(val.y - mx);
    ex.z = __expf(val.z - mx);
    ex.w = __expf(val.w - mx);
#pragma unroll
    for (int o = 8; o > 0; o >>= 1) {
      ex.x += __shfl_xor(ex.x, o, 64);
      ex.y += __shfl_xor(ex.y, o, 64);
      ex.z += __shfl_xor(ex.z, o, 64);
      ex.w += __shfl_xor(ex.w, o, 64);
    }
    float sm = (ex.x + ex.z) + (ex.y + ex.w);

    float ls = logf(sm);
    float4 o4;
    o4.x = (val.x - mx) - ls;
    o4.y = (val.y - mx) - ls;
    o4.z = (val.z - mx) - ls;
    o4.w = (val.w - mx) - ls;
    int node = nodeBase + n;
    if (node < N_NODES)
      ((float4*)(out + (size_t)node * 64))[l16] = o4;
  }
}

extern "C" void kernel_launch(void* const* d_in, const int* in_sizes, int n_in,
                              void* d_out, int out_size, void* d_ws, size_t ws_size,
                              hipStream_t stream) {
  const float* x   = (const float*)d_in[0];
  const int*   src = (const int*)d_in[1];
  const int*   dst = (const int*)d_in[2];
  const float* W1  = (const float*)d_in[3];
  const float* b1  = (const float*)d_in[4];
  const float* W2  = (const float*)d_in[5];
  const float* b2  = (const float*)d_in[6];
  float* out = (float*)d_out;
  int E = in_sizes[1];

  int* bcnt   = (int*)d_ws;                 // 1024
  int* bstart = bcnt + NBPAD;               // 1028
  int* bcur   = bstart + 1028;              // 1024
  int* packed = bcur + NBPAD;               // E
  float* mean1 = (float*)(packed + E);      // NPAD*64 (offset stays 16B-aligned)
  float* g     = mean1 + (size_t)NPAD * 64; // NPAD*64

  hipMemsetAsync(bcnt, 0, NBPAD * sizeof(int), stream);
  bhist_kernel<<<(E + 4095) / 4096, 256, 0, stream>>>(dst, bcnt, E);
  bscan_kernel<<<1, 256, 0, stream>>>(bcnt, bstart, bcur);
  bfill_kernel<<<(E + FILL_CHUNK - 1) / FILL_CHUNK, 256, 0, stream>>>(
      src, dst, bcur, packed, E);

  bgather1_kernel<<<NB, 256, 0, stream>>>(x, bstart, packed, mean1);
  mlp_fused_kernel<<<NPAD / 64, 256, 0, stream>>>(mean1, W1, b1, W2, g);
  bgather2_kernel<<<NB, 256, 0, stream>>>(g, bstart, packed, b2, out);
}

// Round 9
// 230.894 us; speedup vs baseline: 3.8199x; 3.8199x over previous
//
#include <hip/hip_runtime.h>

#define N_NODES 50000
#define EPS 1e-6f
#define NB 782          // buckets of 64 nodes: ceil(50000/64)
#define NBPAD 1024
#define NPAD 50048      // N rounded up to 64
#define FILL_CHUNK 12288

// ---------------- Workspace layout (ints then floats) ----------------
// bcnt   : 1024 ints  (zeroed each call; bucket histogram)
// bstart : 1028 ints  (bucket offsets, bstart[NB] = E)
// bcur   : 1024 ints  (bfill cursors)
// off    : 50064 ints (per-node CSR offsets; off[N] = E)
// packed : E ints     ((src<<16)|dst, grouped by bucket)
// ssrc   : E ints     (src ids in per-node CSR order)
// mean1  : NPAD*64 floats
// g      : NPAD*64 floats
//
// NUMERICS CONTRACT: absmax pinned at 0.03125 empirically.
//  - neighbor-sum ORDER is free (rounds 1/5/7/8 all measured 0.03125 under
//    different nondeterministic orders), but per-element EXPRESSIONS are not:
//    gather loop: groups-of-4 (v0+v1)+(v2+v3), tail sequential;
//    mean = acc*dinv, dinv = 1/(deg+EPS); val = acc*dinv + b2;
//    softmax: lane-xor butterfly 8,4,2,1 then (x+z)+(y+w); (val-mx)-logf(sm).
//  - GEMMs: acc init (bias/0), fmaf ascending k, one chain per output.
// SCHEDULE CONTRACT (round-6): constant-trip k-loops containing global loads
// MUST carry #pragma unroll 1 (else full unroll -> VGPR 256 -> scratch spill).
// GATHER CONTRACT (round-8): NO per-edge LDS atomics — ds_add_rtn_f32
// serializes (368 µs vs 45 µs). Register accumulation + wave shuffles only.

#define COMP(v, j) ((j) == 0 ? (v).x : (j) == 1 ? (v).y : (j) == 2 ? (v).z : (v).w)

// ---- Bucket histogram: 782 bins, LDS-staged ----
__global__ __launch_bounds__(256) void bhist_kernel(
    const int* __restrict__ dst, int* __restrict__ bcnt, int E) {
  __shared__ int lb[NBPAD];
  int t = threadIdx.x;
  for (int i = t; i < NBPAD; i += 256) lb[i] = 0;
  __syncthreads();
  int base = blockIdx.x * 4096;
  for (int i = t; i < 4096; i += 256) {
    int e = base + i;
    if (e < E) atomicAdd(&lb[dst[e] >> 6], 1);
  }
  __syncthreads();
  for (int i = t; i < NB; i += 256) {
    int c = lb[i];
    if (c) atomicAdd(&bcnt[i], c);
  }
}

// ---- Bucket scan: one block, 4 bins/thread ----
__global__ __launch_bounds__(256) void bscan_kernel(
    const int* __restrict__ bcnt, int* __restrict__ bstart,
    int* __restrict__ bcur) {
  __shared__ int wsum[4];
  int t = threadIdx.x;
  int i0 = t * 4;
  int v0 = (i0 + 0 < NB) ? bcnt[i0 + 0] : 0;
  int v1 = (i0 + 1 < NB) ? bcnt[i0 + 1] : 0;
  int v2 = (i0 + 2 < NB) ? bcnt[i0 + 2] : 0;
  int v3 = (i0 + 3 < NB) ? bcnt[i0 + 3] : 0;
  int s = ((v0 + v1) + (v2 + v3));
  int lane = t & 63, wv = t >> 6;
  int x = s;
#pragma unroll
  for (int d = 1; d < 64; d <<= 1) {
    int y = __shfl_up(x, d, 64);
    if (lane >= d) x += y;
  }
  if (lane == 63) wsum[wv] = x;
  __syncthreads();
  int add = 0;
  for (int w = 0; w < wv; w++) add += wsum[w];
  int excl = add + x - s;
  int p0 = excl, p1 = p0 + v0, p2 = p1 + v1, p3 = p2 + v2;
  if (i0 + 0 < NB) { bstart[i0 + 0] = p0; bcur[i0 + 0] = p0; }
  if (i0 + 1 < NB) { bstart[i0 + 1] = p1; bcur[i0 + 1] = p1; }
  if (i0 + 2 < NB) { bstart[i0 + 2] = p2; bcur[i0 + 2] = p2; }
  if (i0 + 3 < NB) { bstart[i0 + 3] = p3; bcur[i0 + 3] = p3; }
  if (t == 255) bstart[NB] = excl + s;  // = E
}

// ---- Bucket fill: LDS hist -> one reservation per bucket -> merged scatter
__global__ __launch_bounds__(256) void bfill_kernel(
    const int* __restrict__ src, const int* __restrict__ dst,
    int* __restrict__ bcur, int* __restrict__ packed, int E) {
  __shared__ int lb[NBPAD];
  __shared__ int lcur[NBPAD];
  int t = threadIdx.x;
  for (int i = t; i < NBPAD; i += 256) lb[i] = 0;
  __syncthreads();
  int base = blockIdx.x * FILL_CHUNK;
  int end = base + FILL_CHUNK; if (end > E) end = E;
  for (int e = base + t; e < end; e += 256) atomicAdd(&lb[dst[e] >> 6], 1);
  __syncthreads();
  for (int i = t; i < NB; i += 256) {
    int c = lb[i];
    lcur[i] = c ? atomicAdd(&bcur[i], c) : 0;
  }
  __syncthreads();
  for (int e = base + t; e < end; e += 256) {
    int d = dst[e];
    int pos = atomicAdd(&lcur[d >> 6], 1);
    packed[pos] = (int)(((unsigned)src[e] << 16) | (unsigned)d);
  }
}

// ---- CSR pass 2: one block per bucket; bucket-grouped -> per-node order.
// All writes land inside this bucket's contiguous range -> L2-merged.
__global__ __launch_bounds__(256) void csr_kernel(
    const int* __restrict__ bstart, const int* __restrict__ packed,
    int* __restrict__ off, int* __restrict__ ssrc) {
  __shared__ int lcnt[64];
  __shared__ int lpos[64];
  int t = threadIdx.x;
  if (t < 64) lcnt[t] = 0;
  __syncthreads();
  int b = blockIdx.x;
  int nodeBase = b << 6;
  int eb = bstart[b], ee = bstart[b + 1];
  for (int e = eb + t; e < ee; e += 256) {
    atomicAdd(&lcnt[(packed[e] & 0xffff) - nodeBase], 1);
  }
  __syncthreads();
  if (t < 64) {  // wave 0: exclusive scan of 64 counts
    int v = lcnt[t];
    int x = v;
#pragma unroll
    for (int d = 1; d < 64; d <<= 1) {
      int y = __shfl_up(x, d, 64);
      if (t >= d) x += y;
    }
    int excl = eb + x - v;
    lpos[t] = excl;
    off[nodeBase + t] = excl;
    if (t == 63) off[nodeBase + 64] = eb + x;  // == bstart[b+1]; dup-safe
  }
  __syncthreads();
  for (int e = eb + t; e < ee; e += 256) {
    int p = packed[e];
    int pos = atomicAdd(&lpos[(p & 0xffff) - nodeBase], 1);
    ssrc[pos] = (int)(((unsigned)p) >> 16);
  }
}

// ---- Gather 1 (round-7 verbatim) ----
__global__ __launch_bounds__(256) void gather1_kernel(
    const float* __restrict__ x, const int* __restrict__ off,
    const int* __restrict__ ssrc, float* __restrict__ mean1) {
  int t = threadIdx.x;
  int lane = t & 63;
  int sub = lane >> 4;
  int l16 = lane & 15;
  int node = blockIdx.x * 16 + ((t >> 6) << 2) + sub;
  int srcLane = sub << 4;
  int b = off[node], e = off[node + 1];
  float4 acc = {0.f, 0.f, 0.f, 0.f};
  for (int base = b; base < e; base += 16) {
    int rem = e - base; if (rem > 16) rem = 16;
    int idx = (l16 < rem) ? ssrc[base + l16] : 0;
    int j = 0;
    for (; j + 4 <= rem; j += 4) {
      int s0 = __shfl(idx, srcLane + j, 64);
      int s1 = __shfl(idx, srcLane + j + 1, 64);
      int s2 = __shfl(idx, srcLane + j + 2, 64);
      int s3 = __shfl(idx, srcLane + j + 3, 64);
      float4 v0 = ((const float4*)(x + (size_t)s0 * 64))[l16];
      float4 v1 = ((const float4*)(x + (size_t)s1 * 64))[l16];
      float4 v2 = ((const float4*)(x + (size_t)s2 * 64))[l16];
      float4 v3 = ((const float4*)(x + (size_t)s3 * 64))[l16];
      acc.x += (v0.x + v1.x) + (v2.x + v3.x);
      acc.y += (v0.y + v1.y) + (v2.y + v3.y);
      acc.z += (v0.z + v1.z) + (v2.z + v3.z);
      acc.w += (v0.w + v1.w) + (v2.w + v3.w);
    }
    for (; j < rem; j++) {
      int s = __shfl(idx, srcLane + j, 64);
      float4 v = ((const float4*)(x + (size_t)s * 64))[l16];
      acc.x += v.x; acc.y += v.y; acc.z += v.z; acc.w += v.w;
    }
  }
  float dinv = 1.0f / ((float)(e - b) + EPS);
  float4 o4;
  o4.x = acc.x * dinv; o4.y = acc.y * dinv;
  o4.z = acc.z * dinv; o4.w = acc.w * dinv;
  ((float4*)(mean1 + (size_t)node * 64))[l16] = o4;
}

// ---- Fused MLP (round-7 verbatim) ----
__global__ __launch_bounds__(256, 3) void mlp_fused_kernel(
    const float* __restrict__ mean1, const float* __restrict__ W1,
    const float* __restrict__ b1, const float* __restrict__ W2,
    float* __restrict__ g) {
  __shared__ float sM[64][68];
  __shared__ float sH[64][132];
  int t = threadIdx.x;
  int row0 = blockIdx.x * 64;

  {
    const float4* M4 = (const float4*)(mean1 + (size_t)row0 * 64);
#pragma unroll
    for (int i = 0; i < 4; i++) {
      int idx = t + 256 * i;
      *(float4*)&sM[idx >> 4][(idx & 15) << 2] = M4[idx];
    }
  }
  __syncthreads();

  int tc = t & 15;
  int tr = t >> 4;

  {  // GEMM1 + relu -> sH
    int c = tc << 3;
    int r = tr << 2;
    float acc[4][8];
    float4 bA = *(const float4*)(b1 + c);
    float4 bB = *(const float4*)(b1 + c + 4);
#pragma unroll
    for (int i = 0; i < 4; i++) {
      acc[i][0] = bA.x; acc[i][1] = bA.y; acc[i][2] = bA.z; acc[i][3] = bA.w;
      acc[i][4] = bB.x; acc[i][5] = bB.y; acc[i][6] = bB.z; acc[i][7] = bB.w;
    }
#pragma unroll 1
    for (int k = 0; k < 64; k += 4) {
      float4 a[4];
#pragma unroll
      for (int i = 0; i < 4; i++) a[i] = *(const float4*)&sM[r + i][k];
      float4 wA[4], wB[4];
#pragma unroll
      for (int j = 0; j < 4; j++) {
        const float* wrow = W1 + (size_t)(k + j) * 128 + c;
        wA[j] = *(const float4*)wrow;
        wB[j] = *(const float4*)(wrow + 4);
      }
#pragma unroll
      for (int j = 0; j < 4; j++) {
#pragma unroll
        for (int i = 0; i < 4; i++) {
          float av = COMP(a[i], j);
          acc[i][0] = fmaf(av, wA[j].x, acc[i][0]);
          acc[i][1] = fmaf(av, wA[j].y, acc[i][1]);
          acc[i][2] = fmaf(av, wA[j].z, acc[i][2]);
          acc[i][3] = fmaf(av, wA[j].w, acc[i][3]);
          acc[i][4] = fmaf(av, wB[j].x, acc[i][4]);
          acc[i][5] = fmaf(av, wB[j].y, acc[i][5]);
          acc[i][6] = fmaf(av, wB[j].z, acc[i][6]);
          acc[i][7] = fmaf(av, wB[j].w, acc[i][7]);
        }
      }
    }
#pragma unroll
    for (int i = 0; i < 4; i++) {
      float4 h0, h1v;
      h0.x = fmaxf(acc[i][0], 0.f); h0.y = fmaxf(acc[i][1], 0.f);
      h0.z = fmaxf(acc[i][2], 0.f); h0.w = fmaxf(acc[i][3], 0.f);
      h1v.x = fmaxf(acc[i][4], 0.f); h1v.y = fmaxf(acc[i][5], 0.f);
      h1v.z = fmaxf(acc[i][6], 0.f); h1v.w = fmaxf(acc[i][7], 0.f);
      *(float4*)&sH[r + i][c] = h0;
      *(float4*)&sH[r + i][c + 4] = h1v;
    }
  }
  __syncthreads();

  {  // GEMM2 -> g
    int c = tc << 2;
    int r = tr << 2;
    float acc[4][4];
#pragma unroll
    for (int i = 0; i < 4; i++)
      acc[i][0] = acc[i][1] = acc[i][2] = acc[i][3] = 0.f;
#pragma unroll 1
    for (int k = 0; k < 128; k += 4) {
      float4 a[4];
#pragma unroll
      for (int i = 0; i < 4; i++) a[i] = *(const float4*)&sH[r + i][k];
      float4 w[4];
#pragma unroll
      for (int j = 0; j < 4; j++)
        w[j] = *(const float4*)(W2 + (size_t)(k + j) * 64 + c);
#pragma unroll
      for (int j = 0; j < 4; j++) {
#pragma unroll
        for (int i = 0; i < 4; i++) {
          float av = COMP(a[i], j);
          acc[i][0] = fmaf(av, w[j].x, acc[i][0]);
          acc[i][1] = fmaf(av, w[j].y, acc[i][1]);
          acc[i][2] = fmaf(av, w[j].z, acc[i][2]);
          acc[i][3] = fmaf(av, w[j].w, acc[i][3]);
        }
      }
    }
#pragma unroll
    for (int i = 0; i < 4; i++) {
      int row = row0 + r + i;
      if (row < N_NODES) {
        float4 o4;
        o4.x = acc[i][0]; o4.y = acc[i][1]; o4.z = acc[i][2]; o4.w = acc[i][3];
        *(float4*)(g + (size_t)row * 64 + c) = o4;
      }
    }
  }
}

// ---- Gather 2 + bias + log_softmax (round-7 verbatim) ----
__global__ __launch_bounds__(256) void gather2_kernel(
    const float* __restrict__ g, const int* __restrict__ off,
    const int* __restrict__ ssrc, const float* __restrict__ b2,
    float* __restrict__ out) {
  int t = threadIdx.x;
  int lane = t & 63;
  int sub = lane >> 4;
  int l16 = lane & 15;
  int node = blockIdx.x * 16 + ((t >> 6) << 2) + sub;
  int srcLane = sub << 4;
  int b = off[node], e = off[node + 1];
  float4 acc = {0.f, 0.f, 0.f, 0.f};
  for (int base = b; base < e; base += 16) {
    int rem = e - base; if (rem > 16) rem = 16;
    int idx = (l16 < rem) ? ssrc[base + l16] : 0;
    int j = 0;
    for (; j + 4 <= rem; j += 4) {
      int s0 = __shfl(idx, srcLane + j, 64);
      int s1 = __shfl(idx, srcLane + j + 1, 64);
      int s2 = __shfl(idx, srcLane + j + 2, 64);
      int s3 = __shfl(idx, srcLane + j + 3, 64);
      float4 v0 = ((const float4*)(g + (size_t)s0 * 64))[l16];
      float4 v1 = ((const float4*)(g + (size_t)s1 * 64))[l16];
      float4 v2 = ((const float4*)(g + (size_t)s2 * 64))[l16];
      float4 v3 = ((const float4*)(g + (size_t)s3 * 64))[l16];
      acc.x += (v0.x + v1.x) + (v2.x + v3.x);
      acc.y += (v0.y + v1.y) + (v2.y + v3.y);
      acc.z += (v0.z + v1.z) + (v2.z + v3.z);
      acc.w += (v0.w + v1.w) + (v2.w + v3.w);
    }
    for (; j < rem; j++) {
      int s = __shfl(idx, srcLane + j, 64);
      float4 v = ((const float4*)(g + (size_t)s * 64))[l16];
      acc.x += v.x; acc.y += v.y; acc.z += v.z; acc.w += v.w;
    }
  }
  float dinv = 1.0f / ((float)(e - b) + EPS);
  float4 b2v = ((const float4*)b2)[l16];
  float4 val;
  val.x = acc.x * dinv + b2v.x;
  val.y = acc.y * dinv + b2v.y;
  val.z = acc.z * dinv + b2v.z;
  val.w = acc.w * dinv + b2v.w;

  float4 m = val;
#pragma unroll
  for (int o = 8; o > 0; o >>= 1) {
    m.x = fmaxf(m.x, __shfl_xor(m.x, o, 64));
    m.y = fmaxf(m.y, __shfl_xor(m.y, o, 64));
    m.z = fmaxf(m.z, __shfl_xor(m.z, o, 64));
    m.w = fmaxf(m.w, __shfl_xor(m.w, o, 64));
  }
  float mx = fmaxf(fmaxf(m.x, m.z), fmaxf(m.y, m.w));

  float4 ex;
  ex.x = __expf(val.x - mx);
  ex.y = __expf(val.y - mx);
  ex.z = __expf(val.z - mx);
  ex.w = __expf(val.w - mx);
#pragma unroll
  for (int o = 8; o > 0; o >>= 1) {
    ex.x += __shfl_xor(ex.x, o, 64);
    ex.y += __shfl_xor(ex.y, o, 64);
    ex.z += __shfl_xor(ex.z, o, 64);
    ex.w += __shfl_xor(ex.w, o, 64);
  }
  float sm = (ex.x + ex.z) + (ex.y + ex.w);

  float ls = logf(sm);
  float4 o4;
  o4.x = (val.x - mx) - ls;
  o4.y = (val.y - mx) - ls;
  o4.z = (val.z - mx) - ls;
  o4.w = (val.w - mx) - ls;
  ((float4*)(out + (size_t)node * 64))[l16] = o4;
}

extern "C" void kernel_launch(void* const* d_in, const int* in_sizes, int n_in,
                              void* d_out, int out_size, void* d_ws, size_t ws_size,
                              hipStream_t stream) {
  const float* x   = (const float*)d_in[0];
  const int*   src = (const int*)d_in[1];
  const int*   dst = (const int*)d_in[2];
  const float* W1  = (const float*)d_in[3];
  const float* b1  = (const float*)d_in[4];
  const float* W2  = (const float*)d_in[5];
  const float* b2  = (const float*)d_in[6];
  float* out = (float*)d_out;
  int E = in_sizes[1];

  int* bcnt   = (int*)d_ws;                  // 1024
  int* bstart = bcnt + NBPAD;                // 1028
  int* bcur   = bstart + 1028;               // 1024
  int* off    = bcur + NBPAD;                // 50064 (>= N+1, 16B-aligned)
  int* packed = off + 50064;                 // E
  int* ssrc   = packed + E;                  // E
  float* mean1 = (float*)(ssrc + E);         // NPAD*64
  float* g     = mean1 + (size_t)NPAD * 64;  // NPAD*64

  hipMemsetAsync(bcnt, 0, NBPAD * sizeof(int), stream);
  bhist_kernel<<<(E + 4095) / 4096, 256, 0, stream>>>(dst, bcnt, E);
  bscan_kernel<<<1, 256, 0, stream>>>(bcnt, bstart, bcur);
  bfill_kernel<<<(E + FILL_CHUNK - 1) / FILL_CHUNK, 256, 0, stream>>>(
      src, dst, bcur, packed, E);
  csr_kernel<<<NB, 256, 0, stream>>>(bstart, packed, off, ssrc);

  gather1_kernel<<<N_NODES / 16, 256, 0, stream>>>(x, off, ssrc, mean1);
  mlp_fused_kernel<<<NPAD / 64, 256, 0, stream>>>(mean1, W1, b1, W2, g);
  gather2_kernel<<<N_NODES / 16, 256, 0, stream>>>(g, off, ssrc, b2, out);
}

// Round 10
// 214.666 us; speedup vs baseline: 4.1087x; 1.0756x over previous
//
#include <hip/hip_runtime.h>

#define N_NODES 50000
#define EPS 1e-6f
#define NB 782          // buckets of 64 nodes: ceil(50000/64)
#define NBPAD 1024
#define NPAD 50048      // N rounded up to 64
#define FILL_CHUNK 3072   // r10: 12288 -> 3072; 66 blocks starved the grid (2.4% occ)
#define BHIST_CHUNK 2048  // r10: 4096 -> 2048, same reasoning

// ---------------- Workspace layout (ints then floats) ----------------
// bcnt   : 1024 ints  (zeroed each call; bucket histogram)
// bstart : 1028 ints  (bucket offsets, bstart[NB] = E)
// bcur   : 1024 ints  (bfill cursors)
// off    : 50064 ints (per-node CSR offsets; off[N] = E)
// packed : E ints     ((src<<16)|dst, grouped by bucket)
// ssrc   : E ints     (src ids in per-node CSR order)
// mean1  : NPAD*64 floats
// g      : NPAD*64 floats
//
// NUMERICS CONTRACT: absmax pinned at 0.03125 empirically.
//  - neighbor-sum ORDER is free (rounds 1/5/7/8/9 all measured 0.03125 under
//    different nondeterministic orders), but per-element EXPRESSIONS are not:
//    gather loop: groups-of-4 (v0+v1)+(v2+v3), tail sequential;
//    mean = acc*dinv, dinv = 1/(deg+EPS); val = acc*dinv + b2;
//    softmax: lane-xor butterfly 8,4,2,1 then (x+z)+(y+w); (val-mx)-logf(sm).
//  - GEMMs: acc init (bias/0), fmaf ascending k, one chain per output.
// SCHEDULE CONTRACT (round-6): constant-trip k-loops containing global loads
// MUST carry #pragma unroll 1 (else full unroll -> VGPR 256 -> scratch spill).
// GATHER CONTRACT (round-8): NO per-edge LDS atomics in the float gathers —
// ds_add_rtn_f32 serializes (368 µs vs 45 µs). Register accumulation only.
// GRID CONTRACT (round-9): latency-bound build kernels need >=256 blocks;
// 66 blocks = 2.4% occupancy = 55 µs for 8 MB of traffic.

#define COMP(v, j) ((j) == 0 ? (v).x : (j) == 1 ? (v).y : (j) == 2 ? (v).z : (v).w)

// ---- Bucket histogram: 782 bins, LDS-staged ----
__global__ __launch_bounds__(256) void bhist_kernel(
    const int* __restrict__ dst, int* __restrict__ bcnt, int E) {
  __shared__ int lb[NBPAD];
  int t = threadIdx.x;
  for (int i = t; i < NBPAD; i += 256) lb[i] = 0;
  __syncthreads();
  int base = blockIdx.x * BHIST_CHUNK;
  int end = base + BHIST_CHUNK; if (end > E) end = E;
  for (int e = base + t; e < end; e += 256) atomicAdd(&lb[dst[e] >> 6], 1);
  __syncthreads();
  for (int i = t; i < NB; i += 256) {
    int c = lb[i];
    if (c) atomicAdd(&bcnt[i], c);
  }
}

// ---- Bucket scan: one block, 4 bins/thread ----
__global__ __launch_bounds__(256) void bscan_kernel(
    const int* __restrict__ bcnt, int* __restrict__ bstart,
    int* __restrict__ bcur) {
  __shared__ int wsum[4];
  int t = threadIdx.x;
  int i0 = t * 4;
  int v0 = (i0 + 0 < NB) ? bcnt[i0 + 0] : 0;
  int v1 = (i0 + 1 < NB) ? bcnt[i0 + 1] : 0;
  int v2 = (i0 + 2 < NB) ? bcnt[i0 + 2] : 0;
  int v3 = (i0 + 3 < NB) ? bcnt[i0 + 3] : 0;
  int s = ((v0 + v1) + (v2 + v3));
  int lane = t & 63, wv = t >> 6;
  int x = s;
#pragma unroll
  for (int d = 1; d < 64; d <<= 1) {
    int y = __shfl_up(x, d, 64);
    if (lane >= d) x += y;
  }
  if (lane == 63) wsum[wv] = x;
  __syncthreads();
  int add = 0;
  for (int w = 0; w < wv; w++) add += wsum[w];
  int excl = add + x - s;
  int p0 = excl, p1 = p0 + v0, p2 = p1 + v1, p3 = p2 + v2;
  if (i0 + 0 < NB) { bstart[i0 + 0] = p0; bcur[i0 + 0] = p0; }
  if (i0 + 1 < NB) { bstart[i0 + 1] = p1; bcur[i0 + 1] = p1; }
  if (i0 + 2 < NB) { bstart[i0 + 2] = p2; bcur[i0 + 2] = p2; }
  if (i0 + 3 < NB) { bstart[i0 + 3] = p3; bcur[i0 + 3] = p3; }
  if (t == 255) bstart[NB] = excl + s;  // = E
}

// ---- Bucket fill: LDS hist -> one reservation per bucket -> merged scatter
__global__ __launch_bounds__(256) void bfill_kernel(
    const int* __restrict__ src, const int* __restrict__ dst,
    int* __restrict__ bcur, int* __restrict__ packed, int E) {
  __shared__ int lb[NBPAD];
  __shared__ int lcur[NBPAD];
  int t = threadIdx.x;
  for (int i = t; i < NBPAD; i += 256) lb[i] = 0;
  __syncthreads();
  int base = blockIdx.x * FILL_CHUNK;
  int end = base + FILL_CHUNK; if (end > E) end = E;
  for (int e = base + t; e < end; e += 256) atomicAdd(&lb[dst[e] >> 6], 1);
  __syncthreads();
  for (int i = t; i < NB; i += 256) {
    int c = lb[i];
    lcur[i] = c ? atomicAdd(&bcur[i], c) : 0;
  }
  __syncthreads();
  for (int e = base + t; e < end; e += 256) {
    int d = dst[e];
    int pos = atomicAdd(&lcur[d >> 6], 1);
    packed[pos] = (int)(((unsigned)src[e] << 16) | (unsigned)d);
  }
}

// ---- CSR pass 2: one block per bucket; bucket-grouped -> per-node order.
__global__ __launch_bounds__(256) void csr_kernel(
    const int* __restrict__ bstart, const int* __restrict__ packed,
    int* __restrict__ off, int* __restrict__ ssrc) {
  __shared__ int lcnt[64];
  __shared__ int lpos[64];
  int t = threadIdx.x;
  if (t < 64) lcnt[t] = 0;
  __syncthreads();
  int b = blockIdx.x;
  int nodeBase = b << 6;
  int eb = bstart[b], ee = bstart[b + 1];
  for (int e = eb + t; e < ee; e += 256) {
    atomicAdd(&lcnt[(packed[e] & 0xffff) - nodeBase], 1);
  }
  __syncthreads();
  if (t < 64) {  // wave 0: exclusive scan of 64 counts
    int v = lcnt[t];
    int x = v;
#pragma unroll
    for (int d = 1; d < 64; d <<= 1) {
      int y = __shfl_up(x, d, 64);
      if (t >= d) x += y;
    }
    int excl = eb + x - v;
    lpos[t] = excl;
    off[nodeBase + t] = excl;
    if (t == 63) off[nodeBase + 64] = eb + x;  // == bstart[b+1]; dup-safe
  }
  __syncthreads();
  for (int e = eb + t; e < ee; e += 256) {
    int p = packed[e];
    int pos = atomicAdd(&lpos[(p & 0xffff) - nodeBase], 1);
    ssrc[pos] = (int)(((unsigned)p) >> 16);
  }
}

// ---- Gather 1 (round-7 verbatim) ----
__global__ __launch_bounds__(256) void gather1_kernel(
    const float* __restrict__ x, const int* __restrict__ off,
    const int* __restrict__ ssrc, float* __restrict__ mean1) {
  int t = threadIdx.x;
  int lane = t & 63;
  int sub = lane >> 4;
  int l16 = lane & 15;
  int node = blockIdx.x * 16 + ((t >> 6) << 2) + sub;
  int srcLane = sub << 4;
  int b = off[node], e = off[node + 1];
  float4 acc = {0.f, 0.f, 0.f, 0.f};
  for (int base = b; base < e; base += 16) {
    int rem = e - base; if (rem > 16) rem = 16;
    int idx = (l16 < rem) ? ssrc[base + l16] : 0;
    int j = 0;
    for (; j + 4 <= rem; j += 4) {
      int s0 = __shfl(idx, srcLane + j, 64);
      int s1 = __shfl(idx, srcLane + j + 1, 64);
      int s2 = __shfl(idx, srcLane + j + 2, 64);
      int s3 = __shfl(idx, srcLane + j + 3, 64);
      float4 v0 = ((const float4*)(x + (size_t)s0 * 64))[l16];
      float4 v1 = ((const float4*)(x + (size_t)s1 * 64))[l16];
      float4 v2 = ((const float4*)(x + (size_t)s2 * 64))[l16];
      float4 v3 = ((const float4*)(x + (size_t)s3 * 64))[l16];
      acc.x += (v0.x + v1.x) + (v2.x + v3.x);
      acc.y += (v0.y + v1.y) + (v2.y + v3.y);
      acc.z += (v0.z + v1.z) + (v2.z + v3.z);
      acc.w += (v0.w + v1.w) + (v2.w + v3.w);
    }
    for (; j < rem; j++) {
      int s = __shfl(idx, srcLane + j, 64);
      float4 v = ((const float4*)(x + (size_t)s * 64))[l16];
      acc.x += v.x; acc.y += v.y; acc.z += v.z; acc.w += v.w;
    }
  }
  float dinv = 1.0f / ((float)(e - b) + EPS);
  float4 o4;
  o4.x = acc.x * dinv; o4.y = acc.y * dinv;
  o4.z = acc.z * dinv; o4.w = acc.w * dinv;
  ((float4*)(mean1 + (size_t)node * 64))[l16] = o4;
}

// ---- Fused MLP (round-7 verbatim) ----
__global__ __launch_bounds__(256, 3) void mlp_fused_kernel(
    const float* __restrict__ mean1, const float* __restrict__ W1,
    const float* __restrict__ b1, const float* __restrict__ W2,
    float* __restrict__ g) {
  __shared__ float sM[64][68];
  __shared__ float sH[64][132];
  int t = threadIdx.x;
  int row0 = blockIdx.x * 64;

  {
    const float4* M4 = (const float4*)(mean1 + (size_t)row0 * 64);
#pragma unroll
    for (int i = 0; i < 4; i++) {
      int idx = t + 256 * i;
      *(float4*)&sM[idx >> 4][(idx & 15) << 2] = M4[idx];
    }
  }
  __syncthreads();

  int tc = t & 15;
  int tr = t >> 4;

  {  // GEMM1 + relu -> sH
    int c = tc << 3;
    int r = tr << 2;
    float acc[4][8];
    float4 bA = *(const float4*)(b1 + c);
    float4 bB = *(const float4*)(b1 + c + 4);
#pragma unroll
    for (int i = 0; i < 4; i++) {
      acc[i][0] = bA.x; acc[i][1] = bA.y; acc[i][2] = bA.z; acc[i][3] = bA.w;
      acc[i][4] = bB.x; acc[i][5] = bB.y; acc[i][6] = bB.z; acc[i][7] = bB.w;
    }
#pragma unroll 1
    for (int k = 0; k < 64; k += 4) {
      float4 a[4];
#pragma unroll
      for (int i = 0; i < 4; i++) a[i] = *(const float4*)&sM[r + i][k];
      float4 wA[4], wB[4];
#pragma unroll
      for (int j = 0; j < 4; j++) {
        const float* wrow = W1 + (size_t)(k + j) * 128 + c;
        wA[j] = *(const float4*)wrow;
        wB[j] = *(const float4*)(wrow + 4);
      }
#pragma unroll
      for (int j = 0; j < 4; j++) {
#pragma unroll
        for (int i = 0; i < 4; i++) {
          float av = COMP(a[i], j);
          acc[i][0] = fmaf(av, wA[j].x, acc[i][0]);
          acc[i][1] = fmaf(av, wA[j].y, acc[i][1]);
          acc[i][2] = fmaf(av, wA[j].z, acc[i][2]);
          acc[i][3] = fmaf(av, wA[j].w, acc[i][3]);
          acc[i][4] = fmaf(av, wB[j].x, acc[i][4]);
          acc[i][5] = fmaf(av, wB[j].y, acc[i][5]);
          acc[i][6] = fmaf(av, wB[j].z, acc[i][6]);
          acc[i][7] = fmaf(av, wB[j].w, acc[i][7]);
        }
      }
    }
#pragma unroll
    for (int i = 0; i < 4; i++) {
      float4 h0, h1v;
      h0.x = fmaxf(acc[i][0], 0.f); h0.y = fmaxf(acc[i][1], 0.f);
      h0.z = fmaxf(acc[i][2], 0.f); h0.w = fmaxf(acc[i][3], 0.f);
      h1v.x = fmaxf(acc[i][4], 0.f); h1v.y = fmaxf(acc[i][5], 0.f);
      h1v.z = fmaxf(acc[i][6], 0.f); h1v.w = fmaxf(acc[i][7], 0.f);
      *(float4*)&sH[r + i][c] = h0;
      *(float4*)&sH[r + i][c + 4] = h1v;
    }
  }
  __syncthreads();

  {  // GEMM2 -> g
    int c = tc << 2;
    int r = tr << 2;
    float acc[4][4];
#pragma unroll
    for (int i = 0; i < 4; i++)
      acc[i][0] = acc[i][1] = acc[i][2] = acc[i][3] = 0.f;
#pragma unroll 1
    for (int k = 0; k < 128; k += 4) {
      float4 a[4];
#pragma unroll
      for (int i = 0; i < 4; i++) a[i] = *(const float4*)&sH[r + i][k];
      float4 w[4];
#pragma unroll
      for (int j = 0; j < 4; j++)
        w[j] = *(const float4*)(W2 + (size_t)(k + j) * 64 + c);
#pragma unroll
      for (int j = 0; j < 4; j++) {
#pragma unroll
        for (int i = 0; i < 4; i++) {
          float av = COMP(a[i], j);
          acc[i][0] = fmaf(av, w[j].x, acc[i][0]);
          acc[i][1] = fmaf(av, w[j].y, acc[i][1]);
          acc[i][2] = fmaf(av, w[j].z, acc[i][2]);
          acc[i][3] = fmaf(av, w[j].w, acc[i][3]);
        }
      }
    }
#pragma unroll
    for (int i = 0; i < 4; i++) {
      int row = row0 + r + i;
      if (row < N_NODES) {
        float4 o4;
        o4.x = acc[i][0]; o4.y = acc[i][1]; o4.z = acc[i][2]; o4.w = acc[i][3];
        *(float4*)(g + (size_t)row * 64 + c) = o4;
      }
    }
  }
}

// ---- Gather 2 + bias + log_softmax (round-7 verbatim) ----
__global__ __launch_bounds__(256) void gather2_kernel(
    const float* __restrict__ g, const int* __restrict__ off,
    const int* __restrict__ ssrc, const float* __restrict__ b2,
    float* __restrict__ out) {
  int t = threadIdx.x;
  int lane = t & 63;
  int sub = lane >> 4;
  int l16 = lane & 15;
  int node = blockIdx.x * 16 + ((t >> 6) << 2) + sub;
  int srcLane = sub << 4;
  int b = off[node], e = off[node + 1];
  float4 acc = {0.f, 0.f, 0.f, 0.f};
  for (int base = b; base < e; base += 16) {
    int rem = e - base; if (rem > 16) rem = 16;
    int idx = (l16 < rem) ? ssrc[base + l16] : 0;
    int j = 0;
    for (; j + 4 <= rem; j += 4) {
      int s0 = __shfl(idx, srcLane + j, 64);
      int s1 = __shfl(idx, srcLane + j + 1, 64);
      int s2 = __shfl(idx, srcLane + j + 2, 64);
      int s3 = __shfl(idx, srcLane + j + 3, 64);
      float4 v0 = ((const float4*)(g + (size_t)s0 * 64))[l16];
      float4 v1 = ((const float4*)(g + (size_t)s1 * 64))[l16];
      float4 v2 = ((const float4*)(g + (size_t)s2 * 64))[l16];
      float4 v3 = ((const float4*)(g + (size_t)s3 * 64))[l16];
      acc.x += (v0.x + v1.x) + (v2.x + v3.x);
      acc.y += (v0.y + v1.y) + (v2.y + v3.y);
      acc.z += (v0.z + v1.z) + (v2.z + v3.z);
      acc.w += (v0.w + v1.w) + (v2.w + v3.w);
    }
    for (; j < rem; j++) {
      int s = __shfl(idx, srcLane + j, 64);
      float4 v = ((const float4*)(g + (size_t)s * 64))[l16];
      acc.x += v.x; acc.y += v.y; acc.z += v.z; acc.w += v.w;
    }
  }
  float dinv = 1.0f / ((float)(e - b) + EPS);
  float4 b2v = ((const float4*)b2)[l16];
  float4 val;
  val.x = acc.x * dinv + b2v.x;
  val.y = acc.y * dinv + b2v.y;
  val.z = acc.z * dinv + b2v.z;
  val.w = acc.w * dinv + b2v.w;

  float4 m = val;
#pragma unroll
  for (int o = 8; o > 0; o >>= 1) {
    m.x = fmaxf(m.x, __shfl_xor(m.x, o, 64));
    m.y = fmaxf(m.y, __shfl_xor(m.y, o, 64));
    m.z = fmaxf(m.z, __shfl_xor(m.z, o, 64));
    m.w = fmaxf(m.w, __shfl_xor(m.w, o, 64));
  }
  float mx = fmaxf(fmaxf(m.x, m.z), fmaxf(m.y, m.w));

  float4 ex;
  ex.x = __expf(val.x - mx);
  ex.y = __expf(val.y - mx);
  ex.z = __expf(val.z - mx);
  ex.w = __expf(val.w - mx);
#pragma unroll
  for (int o = 8; o > 0; o >>= 1) {
    ex.x += __shfl_xor(ex.x, o, 64);
    ex.y += __shfl_xor(ex.y, o, 64);
    ex.z += __shfl_xor(ex.z, o, 64);
    ex.w += __shfl_xor(ex.w, o, 64);
  }
  float sm = (ex.x + ex.z) + (ex.y + ex.w);

  float ls = logf(sm);
  float4 o4;
  o4.x = (val.x - mx) - ls;
  o4.y = (val.y - mx) - ls;
  o4.z = (val.z - mx) - ls;
  o4.w = (val.w - mx) - ls;
  ((float4*)(out + (size_t)node * 64))[l16] = o4;
}

extern "C" void kernel_launch(void* const* d_in, const int* in_sizes, int n_in,
                              void* d_out, int out_size, void* d_ws, size_t ws_size,
                              hipStream_t stream) {
  const float* x   = (const float*)d_in[0];
  const int*   src = (const int*)d_in[1];
  const int*   dst = (const int*)d_in[2];
  const float* W1  = (const float*)d_in[3];
  const float* b1  = (const float*)d_in[4];
  const float* W2  = (const float*)d_in[5];
  const float* b2  = (const float*)d_in[6];
  float* out = (float*)d_out;
  int E = in_sizes[1];

  int* bcnt   = (int*)d_ws;                  // 1024
  int* bstart = bcnt + NBPAD;                // 1028
  int* bcur   = bstart + 1028;               // 1024
  int* off    = bcur + NBPAD;                // 50064 (>= N+1, 16B-aligned)
  int* packed = off + 50064;                 // E
  int* ssrc   = packed + E;                  // E
  float* mean1 = (float*)(ssrc + E);         // NPAD*64
  float* g     = mean1 + (size_t)NPAD * 64;  // NPAD*64

  hipMemsetAsync(bcnt, 0, NBPAD * sizeof(int), stream);
  bhist_kernel<<<(E + BHIST_CHUNK - 1) / BHIST_CHUNK, 256, 0, stream>>>(dst, bcnt, E);
  bscan_kernel<<<1, 256, 0, stream>>>(bcnt, bstart, bcur);
  bfill_kernel<<<(E + FILL_CHUNK - 1) / FILL_CHUNK, 256, 0, stream>>>(
      src, dst, bcur, packed, E);
  csr_kernel<<<NB, 256, 0, stream>>>(bstart, packed, off, ssrc);

  gather1_kernel<<<N_NODES / 16, 256, 0, stream>>>(x, off, ssrc, mean1);
  mlp_fused_kernel<<<NPAD / 64, 256, 0, stream>>>(mean1, W1, b1, W2, g);
  gather2_kernel<<<N_NODES / 16, 256, 0, stream>>>(g, off, ssrc, b2, out);
}

// Round 11
// 214.554 us; speedup vs baseline: 4.1108x; 1.0005x over previous
//
#include <hip/hip_runtime.h>

#define N_NODES 50000
#define EPS 1e-6f
#define NB 782          // buckets of 64 nodes: ceil(50000/64)
#define NBPAD 1024
#define NPAD 50048      // N rounded up to 64
#define FILL_CHUNK 3072
#define BHIST_CHUNK 2048

// ---------------- Workspace layout (ints then floats) ----------------
// bcnt   : 1024 ints  (zeroed each call; bucket histogram)
// bstart : 1028 ints  (bucket offsets, bstart[NB] = E)
// bcur   : 1024 ints  (bfill cursors)
// off    : 50064 ints (per-node CSR offsets; off[N] = E)
// packed : E ints     ((src<<16)|dst, grouped by bucket)
// ssrc   : E ints     (src ids in per-node CSR order)
// mean1  : NPAD*64 floats
// g      : NPAD*64 floats
//
// NUMERICS CONTRACT: absmax pinned at 0.03125 empirically.
//  - neighbor-sum ORDER is free across nodes/edges only in *which thread*
//    computes it; per-node per-feature the ADD SEQUENCE is fixed:
//    groups-of-4 (v0+v1)+(v2+v3) ascending, tail sequential. Loads may be
//    batched/reordered freely (pure reads).
//    mean = acc*dinv, dinv = 1/(deg+EPS); val = acc*dinv + b2;
//    softmax: lane-xor butterfly 8,4,2,1 then (x+z)+(y+w); (val-mx)-logf(sm).
//  - GEMMs: acc init (bias/0), fmaf ascending k, one chain per output.
// SCHEDULE CONTRACT (round-6): constant-trip k-loops containing global loads
// MUST carry #pragma unroll 1 (else full unroll -> VGPR 256 -> scratch spill).
// GATHER CONTRACT (round-8): NO per-edge LDS atomics in the float gathers.
// GRID CONTRACT (round-9): latency-bound build kernels need >=256 blocks.
// MLP CONTRACT (round-11): batch 8 row-loads in flight per wave before
// consuming (Little's law at L3 latency); adds stay in contract order.

#define COMP(v, j) ((j) == 0 ? (v).x : (j) == 1 ? (v).y : (j) == 2 ? (v).z : (v).w)

// ---- Bucket histogram ----
__global__ __launch_bounds__(256) void bhist_kernel(
    const int* __restrict__ dst, int* __restrict__ bcnt, int E) {
  __shared__ int lb[NBPAD];
  int t = threadIdx.x;
  for (int i = t; i < NBPAD; i += 256) lb[i] = 0;
  __syncthreads();
  int base = blockIdx.x * BHIST_CHUNK;
  int end = base + BHIST_CHUNK; if (end > E) end = E;
  for (int e = base + t; e < end; e += 256) atomicAdd(&lb[dst[e] >> 6], 1);
  __syncthreads();
  for (int i = t; i < NB; i += 256) {
    int c = lb[i];
    if (c) atomicAdd(&bcnt[i], c);
  }
}

// ---- Bucket scan ----
__global__ __launch_bounds__(256) void bscan_kernel(
    const int* __restrict__ bcnt, int* __restrict__ bstart,
    int* __restrict__ bcur) {
  __shared__ int wsum[4];
  int t = threadIdx.x;
  int i0 = t * 4;
  int v0 = (i0 + 0 < NB) ? bcnt[i0 + 0] : 0;
  int v1 = (i0 + 1 < NB) ? bcnt[i0 + 1] : 0;
  int v2 = (i0 + 2 < NB) ? bcnt[i0 + 2] : 0;
  int v3 = (i0 + 3 < NB) ? bcnt[i0 + 3] : 0;
  int s = ((v0 + v1) + (v2 + v3));
  int lane = t & 63, wv = t >> 6;
  int x = s;
#pragma unroll
  for (int d = 1; d < 64; d <<= 1) {
    int y = __shfl_up(x, d, 64);
    if (lane >= d) x += y;
  }
  if (lane == 63) wsum[wv] = x;
  __syncthreads();
  int add = 0;
  for (int w = 0; w < wv; w++) add += wsum[w];
  int excl = add + x - s;
  int p0 = excl, p1 = p0 + v0, p2 = p1 + v1, p3 = p2 + v2;
  if (i0 + 0 < NB) { bstart[i0 + 0] = p0; bcur[i0 + 0] = p0; }
  if (i0 + 1 < NB) { bstart[i0 + 1] = p1; bcur[i0 + 1] = p1; }
  if (i0 + 2 < NB) { bstart[i0 + 2] = p2; bcur[i0 + 2] = p2; }
  if (i0 + 3 < NB) { bstart[i0 + 3] = p3; bcur[i0 + 3] = p3; }
  if (t == 255) bstart[NB] = excl + s;  // = E
}

// ---- Bucket fill ----
__global__ __launch_bounds__(256) void bfill_kernel(
    const int* __restrict__ src, const int* __restrict__ dst,
    int* __restrict__ bcur, int* __restrict__ packed, int E) {
  __shared__ int lb[NBPAD];
  __shared__ int lcur[NBPAD];
  int t = threadIdx.x;
  for (int i = t; i < NBPAD; i += 256) lb[i] = 0;
  __syncthreads();
  int base = blockIdx.x * FILL_CHUNK;
  int end = base + FILL_CHUNK; if (end > E) end = E;
  for (int e = base + t; e < end; e += 256) atomicAdd(&lb[dst[e] >> 6], 1);
  __syncthreads();
  for (int i = t; i < NB; i += 256) {
    int c = lb[i];
    lcur[i] = c ? atomicAdd(&bcur[i], c) : 0;
  }
  __syncthreads();
  for (int e = base + t; e < end; e += 256) {
    int d = dst[e];
    int pos = atomicAdd(&lcur[d >> 6], 1);
    packed[pos] = (int)(((unsigned)src[e] << 16) | (unsigned)d);
  }
}

// ---- CSR pass 2 ----
__global__ __launch_bounds__(256) void csr_kernel(
    const int* __restrict__ bstart, const int* __restrict__ packed,
    int* __restrict__ off, int* __restrict__ ssrc) {
  __shared__ int lcnt[64];
  __shared__ int lpos[64];
  int t = threadIdx.x;
  if (t < 64) lcnt[t] = 0;
  __syncthreads();
  int b = blockIdx.x;
  int nodeBase = b << 6;
  int eb = bstart[b], ee = bstart[b + 1];
  for (int e = eb + t; e < ee; e += 256) {
    atomicAdd(&lcnt[(packed[e] & 0xffff) - nodeBase], 1);
  }
  __syncthreads();
  if (t < 64) {
    int v = lcnt[t];
    int x = v;
#pragma unroll
    for (int d = 1; d < 64; d <<= 1) {
      int y = __shfl_up(x, d, 64);
      if (t >= d) x += y;
    }
    int excl = eb + x - v;
    lpos[t] = excl;
    off[nodeBase + t] = excl;
    if (t == 63) off[nodeBase + 64] = eb + x;
  }
  __syncthreads();
  for (int e = eb + t; e < ee; e += 256) {
    int p = packed[e];
    int pos = atomicAdd(&lpos[(p & 0xffff) - nodeBase], 1);
    ssrc[pos] = (int)(((unsigned)p) >> 16);
  }
}

// Batched 8-in-flight accumulate of edges [j0, j0+8) — adds in contract order.
#define GATHER8(SRCPTR, SARR, J0)                                         \
  {                                                                       \
    float4 v[8];                                                          \
    _Pragma("unroll")                                                     \
    for (int j = 0; j < 8; j++)                                           \
      v[j] = ((const float4*)((SRCPTR) + (size_t)SARR[(J0) + j] * 64))[l16]; \
    acc.x += (v[0].x + v[1].x) + (v[2].x + v[3].x);                       \
    acc.y += (v[0].y + v[1].y) + (v[2].y + v[3].y);                       \
    acc.z += (v[0].z + v[1].z) + (v[2].z + v[3].z);                       \
    acc.w += (v[0].w + v[1].w) + (v[2].w + v[3].w);                       \
    acc.x += (v[4].x + v[5].x) + (v[6].x + v[7].x);                       \
    acc.y += (v[4].y + v[5].y) + (v[6].y + v[7].y);                       \
    acc.z += (v[4].z + v[5].z) + (v[6].z + v[7].z);                       \
    acc.w += (v[4].w + v[5].w) + (v[6].w + v[7].w);                       \
  }

// ---- Gather 1: mean1[n] = mean of x[neighbors] ----
__global__ __launch_bounds__(256) void gather1_kernel(
    const float* __restrict__ x, const int* __restrict__ off,
    const int* __restrict__ ssrc, float* __restrict__ mean1) {
  int t = threadIdx.x;
  int lane = t & 63;
  int sub = lane >> 4;
  int l16 = lane & 15;
  int node = blockIdx.x * 16 + ((t >> 6) << 2) + sub;
  int srcLane = sub << 4;
  int b = off[node], e = off[node + 1];
  float4 acc = {0.f, 0.f, 0.f, 0.f};
  for (int base = b; base < e; base += 16) {
    int rem = e - base; if (rem > 16) rem = 16;
    int idx = (l16 < rem) ? ssrc[base + l16] : 0;
    if (rem == 16) {
      int s[16];
#pragma unroll
      for (int j = 0; j < 16; j++) s[j] = __shfl(idx, srcLane + j, 64);
      GATHER8(x, s, 0)
      GATHER8(x, s, 8)
    } else {
      int j = 0;
      for (; j + 4 <= rem; j += 4) {
        int s0 = __shfl(idx, srcLane + j, 64);
        int s1 = __shfl(idx, srcLane + j + 1, 64);
        int s2 = __shfl(idx, srcLane + j + 2, 64);
        int s3 = __shfl(idx, srcLane + j + 3, 64);
        float4 v0 = ((const float4*)(x + (size_t)s0 * 64))[l16];
        float4 v1 = ((const float4*)(x + (size_t)s1 * 64))[l16];
        float4 v2 = ((const float4*)(x + (size_t)s2 * 64))[l16];
        float4 v3 = ((const float4*)(x + (size_t)s3 * 64))[l16];
        acc.x += (v0.x + v1.x) + (v2.x + v3.x);
        acc.y += (v0.y + v1.y) + (v2.y + v3.y);
        acc.z += (v0.z + v1.z) + (v2.z + v3.z);
        acc.w += (v0.w + v1.w) + (v2.w + v3.w);
      }
      for (; j < rem; j++) {
        int s = __shfl(idx, srcLane + j, 64);
        float4 v = ((const float4*)(x + (size_t)s * 64))[l16];
        acc.x += v.x; acc.y += v.y; acc.z += v.z; acc.w += v.w;
      }
    }
  }
  float dinv = 1.0f / ((float)(e - b) + EPS);
  float4 o4;
  o4.x = acc.x * dinv; o4.y = acc.y * dinv;
  o4.z = acc.z * dinv; o4.w = acc.w * dinv;
  ((float4*)(mean1 + (size_t)node * 64))[l16] = o4;
}

// ---- Fused MLP (round-7 verbatim) ----
__global__ __launch_bounds__(256, 3) void mlp_fused_kernel(
    const float* __restrict__ mean1, const float* __restrict__ W1,
    const float* __restrict__ b1, const float* __restrict__ W2,
    float* __restrict__ g) {
  __shared__ float sM[64][68];
  __shared__ float sH[64][132];
  int t = threadIdx.x;
  int row0 = blockIdx.x * 64;

  {
    const float4* M4 = (const float4*)(mean1 + (size_t)row0 * 64);
#pragma unroll
    for (int i = 0; i < 4; i++) {
      int idx = t + 256 * i;
      *(float4*)&sM[idx >> 4][(idx & 15) << 2] = M4[idx];
    }
  }
  __syncthreads();

  int tc = t & 15;
  int tr = t >> 4;

  {  // GEMM1 + relu -> sH
    int c = tc << 3;
    int r = tr << 2;
    float acc[4][8];
    float4 bA = *(const float4*)(b1 + c);
    float4 bB = *(const float4*)(b1 + c + 4);
#pragma unroll
    for (int i = 0; i < 4; i++) {
      acc[i][0] = bA.x; acc[i][1] = bA.y; acc[i][2] = bA.z; acc[i][3] = bA.w;
      acc[i][4] = bB.x; acc[i][5] = bB.y; acc[i][6] = bB.z; acc[i][7] = bB.w;
    }
#pragma unroll 1
    for (int k = 0; k < 64; k += 4) {
      float4 a[4];
#pragma unroll
      for (int i = 0; i < 4; i++) a[i] = *(const float4*)&sM[r + i][k];
      float4 wA[4], wB[4];
#pragma unroll
      for (int j = 0; j < 4; j++) {
        const float* wrow = W1 + (size_t)(k + j) * 128 + c;
        wA[j] = *(const float4*)wrow;
        wB[j] = *(const float4*)(wrow + 4);
      }
#pragma unroll
      for (int j = 0; j < 4; j++) {
#pragma unroll
        for (int i = 0; i < 4; i++) {
          float av = COMP(a[i], j);
          acc[i][0] = fmaf(av, wA[j].x, acc[i][0]);
          acc[i][1] = fmaf(av, wA[j].y, acc[i][1]);
          acc[i][2] = fmaf(av, wA[j].z, acc[i][2]);
          acc[i][3] = fmaf(av, wA[j].w, acc[i][3]);
          acc[i][4] = fmaf(av, wB[j].x, acc[i][4]);
          acc[i][5] = fmaf(av, wB[j].y, acc[i][5]);
          acc[i][6] = fmaf(av, wB[j].z, acc[i][6]);
          acc[i][7] = fmaf(av, wB[j].w, acc[i][7]);
        }
      }
    }
#pragma unroll
    for (int i = 0; i < 4; i++) {
      float4 h0, h1v;
      h0.x = fmaxf(acc[i][0], 0.f); h0.y = fmaxf(acc[i][1], 0.f);
      h0.z = fmaxf(acc[i][2], 0.f); h0.w = fmaxf(acc[i][3], 0.f);
      h1v.x = fmaxf(acc[i][4], 0.f); h1v.y = fmaxf(acc[i][5], 0.f);
      h1v.z = fmaxf(acc[i][6], 0.f); h1v.w = fmaxf(acc[i][7], 0.f);
      *(float4*)&sH[r + i][c] = h0;
      *(float4*)&sH[r + i][c + 4] = h1v;
    }
  }
  __syncthreads();

  {  // GEMM2 -> g
    int c = tc << 2;
    int r = tr << 2;
    float acc[4][4];
#pragma unroll
    for (int i = 0; i < 4; i++)
      acc[i][0] = acc[i][1] = acc[i][2] = acc[i][3] = 0.f;
#pragma unroll 1
    for (int k = 0; k < 128; k += 4) {
      float4 a[4];
#pragma unroll
      for (int i = 0; i < 4; i++) a[i] = *(const float4*)&sH[r + i][k];
      float4 w[4];
#pragma unroll
      for (int j = 0; j < 4; j++)
        w[j] = *(const float4*)(W2 + (size_t)(k + j) * 64 + c);
#pragma unroll
      for (int j = 0; j < 4; j++) {
#pragma unroll
        for (int i = 0; i < 4; i++) {
          float av = COMP(a[i], j);
          acc[i][0] = fmaf(av, w[j].x, acc[i][0]);
          acc[i][1] = fmaf(av, w[j].y, acc[i][1]);
          acc[i][2] = fmaf(av, w[j].z, acc[i][2]);
          acc[i][3] = fmaf(av, w[j].w, acc[i][3]);
        }
      }
    }
#pragma unroll
    for (int i = 0; i < 4; i++) {
      int row = row0 + r + i;
      if (row < N_NODES) {
        float4 o4;
        o4.x = acc[i][0]; o4.y = acc[i][1]; o4.z = acc[i][2]; o4.w = acc[i][3];
        *(float4*)(g + (size_t)row * 64 + c) = o4;
      }
    }
  }
}

// ---- Gather 2 + bias + log_softmax ----
__global__ __launch_bounds__(256) void gather2_kernel(
    const float* __restrict__ g, const int* __restrict__ off,
    const int* __restrict__ ssrc, const float* __restrict__ b2,
    float* __restrict__ out) {
  int t = threadIdx.x;
  int lane = t & 63;
  int sub = lane >> 4;
  int l16 = lane & 15;
  int node = blockIdx.x * 16 + ((t >> 6) << 2) + sub;
  int srcLane = sub << 4;
  int b = off[node], e = off[node + 1];
  float4 acc = {0.f, 0.f, 0.f, 0.f};
  for (int base = b; base < e; base += 16) {
    int rem = e - base; if (rem > 16) rem = 16;
    int idx = (l16 < rem) ? ssrc[base + l16] : 0;
    if (rem == 16) {
      int s[16];
#pragma unroll
      for (int j = 0; j < 16; j++) s[j] = __shfl(idx, srcLane + j, 64);
      GATHER8(g, s, 0)
      GATHER8(g, s, 8)
    } else {
      int j = 0;
      for (; j + 4 <= rem; j += 4) {
        int s0 = __shfl(idx, srcLane + j, 64);
        int s1 = __shfl(idx, srcLane + j + 1, 64);
        int s2 = __shfl(idx, srcLane + j + 2, 64);
        int s3 = __shfl(idx, srcLane + j + 3, 64);
        float4 v0 = ((const float4*)(g + (size_t)s0 * 64))[l16];
        float4 v1 = ((const float4*)(g + (size_t)s1 * 64))[l16];
        float4 v2 = ((const float4*)(g + (size_t)s2 * 64))[l16];
        float4 v3 = ((const float4*)(g + (size_t)s3 * 64))[l16];
        acc.x += (v0.x + v1.x) + (v2.x + v3.x);
        acc.y += (v0.y + v1.y) + (v2.y + v3.y);
        acc.z += (v0.z + v1.z) + (v2.z + v3.z);
        acc.w += (v0.w + v1.w) + (v2.w + v3.w);
      }
      for (; j < rem; j++) {
        int s = __shfl(idx, srcLane + j, 64);
        float4 v = ((const float4*)(g + (size_t)s * 64))[l16];
        acc.x += v.x; acc.y += v.y; acc.z += v.z; acc.w += v.w;
      }
    }
  }
  float dinv = 1.0f / ((float)(e - b) + EPS);
  float4 b2v = ((const float4*)b2)[l16];
  float4 val;
  val.x = acc.x * dinv + b2v.x;
  val.y = acc.y * dinv + b2v.y;
  val.z = acc.z * dinv + b2v.z;
  val.w = acc.w * dinv + b2v.w;

  float4 m = val;
#pragma unroll
  for (int o = 8; o > 0; o >>= 1) {
    m.x = fmaxf(m.x, __shfl_xor(m.x, o, 64));
    m.y = fmaxf(m.y, __shfl_xor(m.y, o, 64));
    m.z = fmaxf(m.z, __shfl_xor(m.z, o, 64));
    m.w = fmaxf(m.w, __shfl_xor(m.w, o, 64));
  }
  float mx = fmaxf(fmaxf(m.x, m.z), fmaxf(m.y, m.w));

  float4 ex;
  ex.x = __expf(val.x - mx);
  ex.y = __expf(val.y - mx);
  ex.z = __expf(val.z - mx);
  ex.w = __expf(val.w - mx);
#pragma unroll
  for (int o = 8; o > 0; o >>= 1) {
    ex.x += __shfl_xor(ex.x, o, 64);
    ex.y += __shfl_xor(ex.y, o, 64);
    ex.z += __shfl_xor(ex.z, o, 64);
    ex.w += __shfl_xor(ex.w, o, 64);
  }
  float sm = (ex.x + ex.z) + (ex.y + ex.w);

  float ls = logf(sm);
  float4 o4;
  o4.x = (val.x - mx) - ls;
  o4.y = (val.y - mx) - ls;
  o4.z = (val.z - mx) - ls;
  o4.w = (val.w - mx) - ls;
  ((float4*)(out + (size_t)node * 64))[l16] = o4;
}

extern "C" void kernel_launch(void* const* d_in, const int* in_sizes, int n_in,
                              void* d_out, int out_size, void* d_ws, size_t ws_size,
                              hipStream_t stream) {
  const float* x   = (const float*)d_in[0];
  const int*   src = (const int*)d_in[1];
  const int*   dst = (const int*)d_in[2];
  const float* W1  = (const float*)d_in[3];
  const float* b1  = (const float*)d_in[4];
  const float* W2  = (const float*)d_in[5];
  const float* b2  = (const float*)d_in[6];
  float* out = (float*)d_out;
  int E = in_sizes[1];

  int* bcnt   = (int*)d_ws;                  // 1024
  int* bstart = bcnt + NBPAD;                // 1028
  int* bcur   = bstart + 1028;               // 1024
  int* off    = bcur + NBPAD;                // 50064
  int* packed = off + 50064;                 // E
  int* ssrc   = packed + E;                  // E
  float* mean1 = (float*)(ssrc + E);         // NPAD*64
  float* g     = mean1 + (size_t)NPAD * 64;  // NPAD*64

  hipMemsetAsync(bcnt, 0, NBPAD * sizeof(int), stream);
  bhist_kernel<<<(E + BHIST_CHUNK - 1) / BHIST_CHUNK, 256, 0, stream>>>(dst, bcnt, E);
  bscan_kernel<<<1, 256, 0, stream>>>(bcnt, bstart, bcur);
  bfill_kernel<<<(E + FILL_CHUNK - 1) / FILL_CHUNK, 256, 0, stream>>>(
      src, dst, bcur, packed, E);
  csr_kernel<<<NB, 256, 0, stream>>>(bstart, packed, off, ssrc);

  gather1_kernel<<<N_NODES / 16, 256, 0, stream>>>(x, off, ssrc, mean1);
  mlp_fused_kernel<<<NPAD / 64, 256, 0, stream>>>(mean1, W1, b1, W2, g);
  gather2_kernel<<<N_NODES / 16, 256, 0, stream>>>(g, off, ssrc, b2, out);
}